// Round 7
// baseline (185.756 us; speedup 1.0000x reference)
//
#include <hip/hip_runtime.h>

// Propagation: E = softsign(V V^T / sqrt(D)); out0 = E @ state; out1 = E @ V
// B=4, N=4096, D=256, fp32 in/out.
//
// Round 7:
//  - GEMM1 computes S^T (operand swap: A=vj frags from LDS, B=Vi registers),
//    so each lane holds E[i=ic*16+l16][j=ja*16+quad*4+r] == exactly what's
//    needed to assemble GEMM2's A-operand (m=l16, k=quad*8+j') INTRA-WAVE via
//    16 __shfl + 8 selects. Esh LDS round-trip eliminated -> barrier B2 gone.
//  - ONE barrier/iter: vj+vjt double-buffered (134 KB LDS); stage(k+1) issues
//    at top of iter k, drained by the single end-of-iter barrier (full-iter
//    prefetch window).
//  - GEMM2: per-wave K = its own 32-j slice (full-rate 16x16x32, kstep=1);
//    dv = 32i x 256d = 128 acc/lane; conjugate j-half wave pairs summed once
//    at the end through LDS (stride-260 padded).
//  - grid 256 = b(4) x it(32, 128-row) x jh(2); partials + combine (R6).
//  - fallback: round-1 fused kernel if ws too small.

#define B_  4
#define N_  4096
#define D_  256

typedef __attribute__((ext_vector_type(8))) short short8;
typedef __attribute__((ext_vector_type(4))) float floatx4;

__device__ __forceinline__ unsigned short f2bf(float f) {
    unsigned int u = __float_as_uint(f);
    u += 0x7fff + ((u >> 16) & 1);   // RTNE
    return (unsigned short)(u >> 16);
}

__device__ __forceinline__ void gl_lds16(const void* g, void* l) {
    __builtin_amdgcn_global_load_lds(
        (const __attribute__((address_space(1))) unsigned int*)g,
        (__attribute__((address_space(3))) unsigned int*)l, 16, 0, 0);
}
__device__ __forceinline__ void gl_lds4(const void* g, void* l) {
    __builtin_amdgcn_global_load_lds(
        (const __attribute__((address_space(1))) unsigned int*)g,
        (__attribute__((address_space(3))) unsigned int*)l, 4, 0, 0);
}

// ---------------- pre-pass: fp32 -> bf16, plus transpose ----------------
__global__ __launch_bounds__(256)
void prepass_kernel(const float* __restrict__ val,
                    unsigned short* __restrict__ Vb,
                    unsigned short* __restrict__ VT) {
    __shared__ unsigned short tile[64][68];
    const int t   = threadIdx.x;
    const int blk = blockIdx.x;            // b*256 + it*4 + dt
    const int b   = blk >> 8;
    const int it  = (blk >> 2) & 63;
    const int dt  = blk & 3;
    const int i0  = it * 64, d0 = dt * 64;
    const float*    vb  = val + (size_t)b * N_ * D_;
    unsigned short* Vbb = Vb  + (size_t)b * N_ * D_;
    unsigned short* VTb = VT  + (size_t)b * D_ * N_;

    #pragma unroll
    for (int q = 0; q < 4; ++q) {
        int idx = t + 256 * q;
        int row = idx >> 4;
        int c4  = idx & 15;
        float4 v = *(const float4*)(vb + (size_t)(i0 + row) * D_ + d0 + c4 * 4);
        ushort4 h;
        h.x = f2bf(v.x); h.y = f2bf(v.y); h.z = f2bf(v.z); h.w = f2bf(v.w);
        *(ushort4*)(Vbb + (size_t)(i0 + row) * D_ + d0 + c4 * 4) = h;
        *(ushort4*)&tile[row][c4 * 4] = h;
    }
    __syncthreads();
    #pragma unroll
    for (int q = 0; q < 4; ++q) {
        int dr = (t >> 4) + q * 16;
        int i4 = t & 15;
        ushort4 h;
        h.x = tile[i4 * 4 + 0][dr];
        h.y = tile[i4 * 4 + 1][dr];
        h.z = tile[i4 * 4 + 2][dr];
        h.w = tile[i4 * 4 + 3][dr];
        *(ushort4*)(VTb + (size_t)(d0 + dr) * N_ + i0 + i4 * 4) = h;
    }
}

// ---------------- main fused kernel ----------------
// grid 256 = b(4) x it(32, 128-row tiles) x jh(2).  512 threads, 8 waves:
// group g = i-half (64 rows); within group w4: r0=(w4>>1)*32 (i), c0=(w4&1)*32 (j).
// LDS (134144 B):
//   vj [buf] : buf*32768            (2 x 32 KB)  [64 j][256 d] granule-swizzled
//   vjt[buf] : 65536 + buf*32768    (2 x 32 KB)  [256 d][64 j] granule-swizzled
//   stj[buf] : 131072 + buf*256     (2 x 256 B)  64 f32
//   dsred    : 133120               (1 KB)       [g][c0h][64] f32
//   dump     : 0 (epilogue overlay) 4 pairs x [32][260] f32 = 133120 B
__global__ __launch_bounds__(512, 1)
void prop_main(const float* __restrict__ state,
               const unsigned short* __restrict__ Vb,
               const unsigned short* __restrict__ VT,
               float* __restrict__ dvp,    // [2][B][N][D] partials
               float* __restrict__ dsp_o)  // [2][B][N]    partials
{
    __shared__ __attribute__((aligned(16))) unsigned char smem[134144];

    const int t    = threadIdx.x;
    const int g    = t >> 8;
    const int w    = t >> 6;
    const int w4   = w & 3;
    const int lane = t & 63;
    const int quad = lane >> 4;
    const int l16  = lane & 15;

    const int x   = blockIdx.x;
    const int b   = x >> 6;
    const int it  = (x >> 1) & 31;
    const int jh  = x & 1;
    const int it0 = it * 128;
    const int jbase = jh * 2048;
    const int niter = 32;

    const unsigned short* Vbb = Vb + (size_t)b * N_ * D_;
    const unsigned short* VTb = VT + (size_t)b * D_ * N_;
    const float*          stb = state + (size_t)b * N_;

    const int hi  = lane >> 5;
    const int p32 = lane & 31;
    const int dr8 = lane >> 3;
    const int p8  = lane & 7;

    int vgoff[4];   // vj staging offsets (ushort units)
    int tgoff[4];   // vjt staging offsets
    #pragma unroll
    for (int n = 0; n < 4; ++n) {
        int r  = 2 * (w * 4 + n) + hi;           // 0..63
        vgoff[n] = r * 256 + (p32 ^ (r & 7)) * 8;
        int d  = 8 * (w * 4 + n) + dr8;          // 0..255
        tgoff[n] = d * 4096 + (p8 ^ dr8) * 8;
    }

    const int r0 = (w4 >> 1) * 32;    // wave's i base within group
    const int c0 = (w4 & 1) * 32;     // wave's j base within tile
    const int pA = l16 & 7;

    // ---- Vi fragments in registers (GEMM1 B-operand; layout == A-frag) ----
    short8 A0[8], A1[8];
    {
        const unsigned short* ar0 = Vbb + (size_t)(it0 + g * 64 + r0 + l16) * 256 + quad * 8;
        const unsigned short* ar1 = ar0 + 16 * 256;
        #pragma unroll
        for (int ks = 0; ks < 8; ++ks) {
            A0[ks] = *(const short8*)(ar0 + ks * 32);
            A1[ks] = *(const short8*)(ar1 + ks * 32);
        }
    }

    // ---- prologue: stage tile 0 into buf0 ----
    #pragma unroll
    for (int n = 0; n < 4; ++n)
        gl_lds16(Vbb + (size_t)jbase * 256 + vgoff[n], smem + (w * 4 + n) * 1024);
    #pragma unroll
    for (int n = 0; n < 4; ++n)
        gl_lds16(VTb + (size_t)jbase + tgoff[n], smem + 65536 + (w * 4 + n) * 1024);
    if (w == 0) gl_lds4(stb + jbase + lane, smem + 131072);
    __syncthreads();

    floatx4 dv[2][16];                // [ic][dt] : 32 i x 256 d partial (own j-slice)
    #pragma unroll
    for (int ic = 0; ic < 2; ++ic)
        #pragma unroll
        for (int dt = 0; dt < 16; ++dt)
            dv[ic][dt] = (floatx4){0.f, 0.f, 0.f, 0.f};
    float dsp[2] = {0.f, 0.f};

    const int src0 = (((2 * quad)     & 3) * 16) + l16;
    const int src1 = (((2 * quad + 1) & 3) * 16) + l16;

    for (int k = 0; k < niter; ++k) {
        const int buf = k & 1;

        // ---- stage tile k+1 into buf^1 (drained by the barrier a full iter later)
        if (k + 1 < niter) {
            const size_t j0n = jbase + (size_t)(k + 1) * 64;
            const int nb = buf ^ 1;
            #pragma unroll
            for (int n = 0; n < 4; ++n)
                gl_lds16(Vbb + j0n * 256 + vgoff[n],
                         smem + nb * 32768 + (w * 4 + n) * 1024);
            #pragma unroll
            for (int n = 0; n < 4; ++n)
                gl_lds16(VTb + j0n + tgoff[n],
                         smem + 65536 + nb * 32768 + (w * 4 + n) * 1024);
            if (w == 0) gl_lds4(stb + j0n + lane, smem + 131072 + nb * 256);
        }

        // ---- GEMM1 (swapped): S^T[j][i] = Vj . Vi^T ----
        const unsigned short* vjb = (const unsigned short*)(smem + buf * 32768);
        floatx4 sa[2][2];             // [ja][ic]
        #pragma unroll
        for (int a = 0; a < 2; ++a)
            #pragma unroll
            for (int c = 0; c < 2; ++c)
                sa[a][c] = (floatx4){0.f, 0.f, 0.f, 0.f};

        #pragma unroll
        for (int ks = 0; ks < 8; ++ks) {
            const int p = ((ks * 4 + quad) ^ pA) * 8;
            short8 a0 = *(const short8*)&vjb[(c0 + l16) * 256 + p];
            short8 a1 = *(const short8*)&vjb[(c0 + 16 + l16) * 256 + p];
            sa[0][0] = __builtin_amdgcn_mfma_f32_16x16x32_bf16(a0, A0[ks], sa[0][0], 0, 0, 0);
            sa[0][1] = __builtin_amdgcn_mfma_f32_16x16x32_bf16(a0, A1[ks], sa[0][1], 0, 0, 0);
            sa[1][0] = __builtin_amdgcn_mfma_f32_16x16x32_bf16(a1, A0[ks], sa[1][0], 0, 0, 0);
            sa[1][1] = __builtin_amdgcn_mfma_f32_16x16x32_bf16(a1, A1[ks], sa[1][1], 0, 0, 0);
        }

        // ---- softsign in-register: e = s/(16+|s|); ds partials; pack to bf16 ----
        const float* stjf = (const float*)(smem + 131072 + buf * 256);
        float4 st0 = *(const float4*)&stjf[c0 + quad * 4];
        float4 st1 = *(const float4*)&stjf[c0 + 16 + quad * 4];
        unsigned int P[2][2][2];      // [ja][ic][h]: packed (e[2h], e[2h+1])
        #pragma unroll
        for (int ja = 0; ja < 2; ++ja) {
            #pragma unroll
            for (int ic = 0; ic < 2; ++ic) {
                float e0 = sa[ja][ic][0] * __builtin_amdgcn_rcpf(16.0f + fabsf(sa[ja][ic][0]));
                float e1 = sa[ja][ic][1] * __builtin_amdgcn_rcpf(16.0f + fabsf(sa[ja][ic][1]));
                float e2 = sa[ja][ic][2] * __builtin_amdgcn_rcpf(16.0f + fabsf(sa[ja][ic][2]));
                float e3 = sa[ja][ic][3] * __builtin_amdgcn_rcpf(16.0f + fabsf(sa[ja][ic][3]));
                const float4 st = ja ? st1 : st0;
                dsp[ic] += e0 * st.x + e1 * st.y + e2 * st.z + e3 * st.w;
                P[ja][ic][0] = (unsigned int)f2bf(e0) | ((unsigned int)f2bf(e1) << 16);
                P[ja][ic][1] = (unsigned int)f2bf(e2) | ((unsigned int)f2bf(e3) << 16);
            }
        }

        // ---- assemble GEMM2 A-frags intra-wave (quad q holds j = 8q..8q+7) ----
        short8 Af[2];
        #pragma unroll
        for (int ic = 0; ic < 2; ++ic) {
            int lo0 = __shfl((int)P[0][ic][0], src0);
            int hi0 = __shfl((int)P[1][ic][0], src0);
            int lo1 = __shfl((int)P[0][ic][1], src0);
            int hi1 = __shfl((int)P[1][ic][1], src0);
            int lo2 = __shfl((int)P[0][ic][0], src1);
            int hi2 = __shfl((int)P[1][ic][0], src1);
            int lo3 = __shfl((int)P[0][ic][1], src1);
            int hi3 = __shfl((int)P[1][ic][1], src1);
            int4 fw;
            fw.x = (quad < 2) ? lo0 : hi0;
            fw.y = (quad < 2) ? lo1 : hi1;
            fw.z = (quad < 2) ? lo2 : hi2;
            fw.w = (quad < 2) ? lo3 : hi3;
            Af[ic] = *(short8*)&fw;
        }

        // ---- GEMM2: dv[32i][256d] += E_slice . Vj (K = own 32 j) ----
        const unsigned short* vjtb = (const unsigned short*)(smem + 65536 + buf * 32768);
        #pragma unroll
        for (int dt = 0; dt < 16; ++dt) {
            const int pos = (((c0 >> 3) + quad) ^ pA) * 8;
            short8 bfr = *(const short8*)&vjtb[(dt * 16 + l16) * 64 + pos];
            dv[0][dt] = __builtin_amdgcn_mfma_f32_16x16x32_bf16(Af[0], bfr, dv[0][dt], 0, 0, 0);
            dv[1][dt] = __builtin_amdgcn_mfma_f32_16x16x32_bf16(Af[1], bfr, dv[1][dt], 0, 0, 0);
        }

        __syncthreads();   // single barrier: drains this iter's LDS reads + next tile's DMA
    }

    // ---- delta_state: reduce over quads, stash per (g, c0-half) ----
    #pragma unroll
    for (int ic = 0; ic < 2; ++ic) {
        float v = dsp[ic];
        v += __shfl_xor(v, 16);
        v += __shfl_xor(v, 32);
        dsp[ic] = v;
    }
    float* dsred = (float*)(smem + 133120);
    if (quad == 0) {
        #pragma unroll
        for (int ic = 0; ic < 2; ++ic)
            dsred[g * 128 + (w4 & 1) * 64 + r0 + ic * 16 + l16] = dsp[ic];
    }

    // ---- delta_val: j-half pair reduce through LDS, then store partial ----
    float* dump = (float*)smem;                 // pair p at p*8320 floats, [32][260]
    const int pair = g * 2 + (w4 >> 1);
    if (w4 & 1) {
        #pragma unroll
        for (int ic = 0; ic < 2; ++ic)
            #pragma unroll
            for (int dt = 0; dt < 16; ++dt)
                #pragma unroll
                for (int r = 0; r < 4; ++r) {
                    const int i32 = ic * 16 + quad * 4 + r;
                    const int d   = dt * 16 + l16;
                    dump[pair * 8320 + i32 * 260 + d] = dv[ic][dt][r];
                }
    }
    __syncthreads();

    if (!(w4 & 1)) {
        float* dvo = dvp + (size_t)jh * B_ * N_ * D_ + (size_t)b * N_ * D_
                         + (size_t)(it0 + g * 64 + r0) * D_;
        #pragma unroll
        for (int ic = 0; ic < 2; ++ic)
            #pragma unroll
            for (int dt = 0; dt < 16; ++dt)
                #pragma unroll
                for (int r = 0; r < 4; ++r) {
                    const int i32 = ic * 16 + quad * 4 + r;
                    const int d   = dt * 16 + l16;
                    dvo[(size_t)i32 * D_ + d] =
                        dv[ic][dt][r] + dump[pair * 8320 + i32 * 260 + d];
                }
    }
    if (t < 128) {
        const int gg = t >> 6;
        const int i  = t & 63;
        dsp_o[(size_t)jh * B_ * N_ + (size_t)b * N_ + it0 + gg * 64 + i]
            = dsred[gg * 128 + i] + dsred[gg * 128 + 64 + i];
    }
}

// ---------------- combine: out = sum of the two j-half partials ----------------
__global__ __launch_bounds__(256)
void combine_kernel(const float4* __restrict__ dv0, const float4* __restrict__ dv1,
                    const float*  __restrict__ ds0, const float*  __restrict__ ds1,
                    float* __restrict__ out) {
    const int NDV4 = B_ * N_ * D_ / 4;   // 1048576
    const int NDS  = B_ * N_;            // 16384
    int x = blockIdx.x * 256 + threadIdx.x;
    if (x < NDV4) {
        float4 a = dv0[x], c = dv1[x];
        float4 r;
        r.x = a.x + c.x; r.y = a.y + c.y; r.z = a.z + c.z; r.w = a.w + c.w;
        ((float4*)(out + NDS))[x] = r;
    } else {
        int y = (x - NDV4) * 4;
        if (y < NDS) {
            float4 a = *(const float4*)(ds0 + y);
            float4 c = *(const float4*)(ds1 + y);
            float4 r;
            r.x = a.x + c.x; r.y = a.y + c.y; r.z = a.z + c.z; r.w = a.w + c.w;
            *(float4*)(out + y) = r;
        }
    }
}

// ---------------- fallback (round-1 kernel, used if ws too small) ----------------
__global__ __launch_bounds__(256, 1)
void prop_kernel_fb(const float* __restrict__ val,
                    const float* __restrict__ state,
                    float* __restrict__ out) {
    __shared__ __attribute__((aligned(16))) unsigned short vi[64][264];
    __shared__ __attribute__((aligned(16))) unsigned short vj[64][264];
    __shared__ __attribute__((aligned(16))) unsigned short vjt[2048][8];
    __shared__ __attribute__((aligned(16))) unsigned short Esh[64][72];
    __shared__ float stj[64];
    __shared__ float dsred[2][64];

    const int t    = threadIdx.x;
    const int w    = t >> 6;
    const int lane = t & 63;
    const int quad = lane >> 4;
    const int l16  = lane & 15;
    const int b   = blockIdx.x >> 6;
    const int it0 = (blockIdx.x & 63) << 6;
    const float* valb = val   + (size_t)b * N_ * D_;
    const float* stb  = state + (size_t)b * N_;

    #pragma unroll
    for (int n = 0; n < 16; ++n) {
        int idx = t + 256 * n;
        int row = idx >> 6;
        int c4  = idx & 63;
        float4 v = *(const float4*)(valb + (size_t)(it0 + row) * D_ + c4 * 4);
        ushort4 h;
        h.x = f2bf(v.x); h.y = f2bf(v.y); h.z = f2bf(v.z); h.w = f2bf(v.w);
        *(ushort4*)&vi[row][c4 * 4] = h;
    }

    const int r0 = (w >> 1) * 32;
    const int c0 = (w & 1) * 32;
    floatx4 dv[4][4];
    #pragma unroll
    for (int a = 0; a < 4; ++a)
        #pragma unroll
        for (int c = 0; c < 4; ++c)
            dv[a][c] = (floatx4){0.f, 0.f, 0.f, 0.f};
    float dsp[8];
    #pragma unroll
    for (int k = 0; k < 8; ++k) dsp[k] = 0.f;

    for (int jt = 0; jt < 64; ++jt) {
        const int j0 = jt * 64;
        #pragma unroll
        for (int n = 0; n < 16; ++n) {
            int idx = t + 256 * n;
            int row = idx >> 6;
            int c4  = idx & 63;
            float4 v = *(const float4*)(valb + (size_t)(j0 + row) * D_ + c4 * 4);
            ushort4 h;
            h.x = f2bf(v.x); h.y = f2bf(v.y); h.z = f2bf(v.z); h.w = f2bf(v.w);
            *(ushort4*)&vj[row][c4 * 4] = h;
        }
        if (t < 64) stj[t] = stb[j0 + t];
        __syncthreads();

        #pragma unroll
        for (int n = 0; n < 8; ++n) {
            const int d  = t;
            const int jb = n;
            short8 pk;
            #pragma unroll
            for (int jj = 0; jj < 8; ++jj) pk[jj] = (short)vj[jb * 8 + jj][d];
            *(short8*)&vjt[d * 8 + (jb ^ (d & 7))][0] = pk;
        }

        floatx4 sa[2][2];
        #pragma unroll
        for (int a = 0; a < 2; ++a)
            #pragma unroll
            for (int c = 0; c < 2; ++c)
                sa[a][c] = (floatx4){0.f, 0.f, 0.f, 0.f};
        #pragma unroll
        for (int ks = 0; ks < 8; ++ks) {
            const int d0 = ks * 32 + quad * 8;
            short8 a0 = *(const short8*)&vi[r0 + l16][d0];
            short8 a1 = *(const short8*)&vi[r0 + 16 + l16][d0];
            short8 b0 = *(const short8*)&vj[c0 + l16][d0];
            short8 b1 = *(const short8*)&vj[c0 + 16 + l16][d0];
            sa[0][0] = __builtin_amdgcn_mfma_f32_16x16x32_bf16(a0, b0, sa[0][0], 0, 0, 0);
            sa[0][1] = __builtin_amdgcn_mfma_f32_16x16x32_bf16(a0, b1, sa[0][1], 0, 0, 0);
            sa[1][0] = __builtin_amdgcn_mfma_f32_16x16x32_bf16(a1, b0, sa[1][0], 0, 0, 0);
            sa[1][1] = __builtin_amdgcn_mfma_f32_16x16x32_bf16(a1, b1, sa[1][1], 0, 0, 0);
        }

        float stc0 = stj[c0 + l16];
        float stc1 = stj[c0 + 16 + l16];
        #pragma unroll
        for (int a = 0; a < 2; ++a) {
            #pragma unroll
            for (int r = 0; r < 4; ++r) {
                const int il = r0 + a * 16 + quad * 4 + r;
                float s0 = sa[a][0][r] * 0.0625f;
                float s1 = sa[a][1][r] * 0.0625f;
                float e0 = s0 / (1.0f + fabsf(s0));
                float e1 = s1 / (1.0f + fabsf(s1));
                dsp[a * 4 + r] += e0 * stc0 + e1 * stc1;
                Esh[il][c0 + l16]      = f2bf(e0);
                Esh[il][c0 + 16 + l16] = f2bf(e1);
            }
        }
        __syncthreads();

        #pragma unroll
        for (int ks = 0; ks < 2; ++ks) {
            short8 af[4], bfr[4];
            #pragma unroll
            for (int a2 = 0; a2 < 4; ++a2)
                af[a2] = *(const short8*)&Esh[a2 * 16 + l16][ks * 32 + quad * 8];
            #pragma unroll
            for (int c2 = 0; c2 < 4; ++c2) {
                const int d  = w * 64 + c2 * 16 + l16;
                const int jb = ks * 4 + quad;
                bfr[c2] = *(const short8*)&vjt[d * 8 + (jb ^ (d & 7))][0];
            }
            #pragma unroll
            for (int a2 = 0; a2 < 4; ++a2)
                #pragma unroll
                for (int c2 = 0; c2 < 4; ++c2)
                    dv[a2][c2] = __builtin_amdgcn_mfma_f32_16x16x32_bf16(af[a2], bfr[c2], dv[a2][c2], 0, 0, 0);
        }
    }

    float* dvo = out + (size_t)B_ * N_ + (size_t)b * N_ * D_;
    #pragma unroll
    for (int a2 = 0; a2 < 4; ++a2)
        #pragma unroll
        for (int c2 = 0; c2 < 4; ++c2)
            #pragma unroll
            for (int r = 0; r < 4; ++r) {
                const int i = it0 + a2 * 16 + quad * 4 + r;
                const int d = w * 64 + c2 * 16 + l16;
                dvo[(size_t)i * D_ + d] = dv[a2][c2][r];
            }

    #pragma unroll
    for (int k = 0; k < 8; ++k) {
        float v = dsp[k];
        v += __shfl_xor(v, 1);
        v += __shfl_xor(v, 2);
        v += __shfl_xor(v, 4);
        v += __shfl_xor(v, 8);
        dsp[k] = v;
    }
    if (l16 == 0) {
        #pragma unroll
        for (int a = 0; a < 2; ++a)
            #pragma unroll
            for (int r = 0; r < 4; ++r) {
                const int row = (w >> 1) * 32 + a * 16 + quad * 4 + r;
                dsred[w & 1][row] = dsp[a * 4 + r];
            }
    }
    __syncthreads();
    if (t < 64) out[(size_t)b * N_ + it0 + t] = dsred[0][t] + dsred[1][t];
}

extern "C" void kernel_launch(void* const* d_in, const int* in_sizes, int n_in,
                              void* d_out, int out_size, void* d_ws, size_t ws_size,
                              hipStream_t stream) {
    const float* val   = (const float*)d_in[0];
    const float* state = (const float*)d_in[1];
    float* out = (float*)d_out;

    const size_t nE         = (size_t)B_ * N_ * D_;                 // 4,194,304
    const size_t need_base  = 2 * nE * sizeof(unsigned short);      // 16.78 MB
    const size_t need_split = need_base + 2 * nE * sizeof(float)
                            + 2 * (size_t)B_ * N_ * sizeof(float);  // ~50.5 MB

    if (ws_size >= need_split) {
        unsigned short* Vb = (unsigned short*)d_ws;
        unsigned short* VT = Vb + nE;
        float* dvp = (float*)(VT + nE);          // [2][B*N*D]
        float* dsp = dvp + 2 * nE;               // [2][B*N]
        prepass_kernel<<<dim3(1024), dim3(256), 0, stream>>>(val, Vb, VT);
        prop_main<<<dim3(256), dim3(512), 0, stream>>>(state, Vb, VT, dvp, dsp);
        const int NDV4 = B_ * N_ * D_ / 4;
        const int NDS4 = B_ * N_ / 4;
        combine_kernel<<<dim3((NDV4 + NDS4) / 256), dim3(256), 0, stream>>>(
            (const float4*)dvp, (const float4*)(dvp + nE),
            dsp, dsp + (size_t)B_ * N_, out);
    } else {
        prop_kernel_fb<<<dim3(256), dim3(256), 0, stream>>>(val, state, out);
    }
}